// Round 12
// baseline (316.089 us; speedup 1.0000x reference)
//
#include <hip/hip_runtime.h>

typedef float f4 __attribute__((ext_vector_type(4)));

static constexpr int Hh = 256, Ww = 256, HW = Hh * Ww;
static constexpr int PLANES = 512;            // N*C
static constexpr int STRIPS = 8;
static constexpr int ROWS   = Hh / STRIPS;    // 32
static constexpr int DEPTH  = 10;
static constexpr int RB     = 4;              // rows advanced per sweep step
static constexpr int NSTEP  = (ROWS + 2 * DEPTH) / RB;   // 13

#if __has_builtin(__builtin_amdgcn_exp2f)
#define EXP2F(x) __builtin_amdgcn_exp2f(x)
#else
#define EXP2F(x) __expf((x) * 0.6931471805599453f)
#endif

static constexpr float LN2 = 0.6931471805599453f;
static constexpr float L2E = 1.4426950408889634f;
static constexpr float AZS = 10.0f * L2E;     // Z = AZS * z  (BETA+log2e folded)

// slrelu pieces in Z-domain (Z = 10*log2e*z):
//   ln(1+p), p = 2^(-|Z|), deg-2 minimax  p*(A1 + A2*p), |err| <= 1.4e-2
//   (error budget OK: absmax saturated at 2.0 across rounds; threshold 10.04)
//   max(Z,0) = (Z + |Z|)/2 folded into linear coefficients.
static constexpr float A1 = 0.9897f;
static constexpr float A2 = -0.3059f;
// t = 1 - 2*slrelu(z) = 1 + TA*Z + TB*az + TC*ln(1+p),  TC = -0.16 exactly
static constexpr float TA = -0.12f * LN2;
static constexpr float TB = -0.08f * LN2;
static constexpr float TCA1 = -0.16f * A1;
static constexpr float TCA2 = -0.16f * A2;
// u = slrelu(z) = UA*Z + UB*az + UC*ln(1+p),  UC = 0.08 exactly
static constexpr float UA = 0.06f * LN2;
static constexpr float UB = 0.04f * LN2;
static constexpr float UCA1 = 0.08f * A1;
static constexpr float UCA2 = 0.08f * A2;

// 6 ops: az, exp2, 4 fma
__device__ __forceinline__ float tval_s(float Z) {
    float az = fabsf(Z);
    float p  = EXP2F(-az);                    // neg folds into src modifier
    float r  = fmaf(TCA2, p, TCA1);
    float s  = fmaf(r, p, 1.0f);              // 1 + TC*ln(1+p)
    return fmaf(TA, Z, fmaf(TB, az, s));
}
// 6 ops
__device__ __forceinline__ float uval_s(float Z) {
    float az = fabsf(Z);
    float p  = EXP2F(-az);
    float r  = fmaf(UCA2, p, UCA1);
    float su = r * p;                         // UC*ln(1+p)
    return fmaf(UA, Z, fmaf(UB, az, su));
}

// One sweep step. BORDER is a literal; pnext[4][4] carries the next step's
// stage-0 rows (prefetched one full step ahead -> no vmcnt stall at stage 0).
#define STEP_BODY(BORDER) do {                                               \
    float og[DEPTH + RB][4];                                                 \
    /* stage-0 rows: consume prefetch (long since returned), scale to Z */   \
    _Pragma("unroll")                                                        \
    for (int m = 0; m < RB; ++m)                                             \
        { _Pragma("unroll") for (int i = 0; i < 4; ++i) og[DEPTH + m][i] = AZS * pnext[m][i]; } \
    /* issue current-step rows og[9]..og[0] in consumption order (raw) */    \
    _Pragma("unroll")                                                        \
    for (int t = DEPTH - 1; t >= 0; --t) {                                   \
        int r = yS - DEPTH + t;                                              \
        if (BORDER) r = r < 0 ? 0 : (r > 255 ? 255 : r);                     \
        f4 v = *reinterpret_cast<const f4*>(op_lane + r * Ww);               \
        og[t][0] = v.x; og[t][1] = v.y; og[t][2] = v.z; og[t][3] = v.w;      \
    }                                                                        \
    /* issue NEXT step's stage-0 prefetch (rows yS+4..yS+7, always clamped) */\
    _Pragma("unroll")                                                        \
    for (int m = 0; m < RB; ++m) {                                           \
        int r = yS + RB + m;                                                 \
        r = r < 0 ? 0 : (r > 255 ? 255 : r);                                 \
        f4 v = *reinterpret_cast<const f4*>(op_lane + r * Ww);               \
        pnext[m][0] = v.x; pnext[m][1] = v.y; pnext[m][2] = v.z; pnext[m][3] = v.w; \
    }                                                                        \
    asm volatile("" ::: "memory");               /* pin loads above compute */\
    float tin[RB][4];                                                        \
    _Pragma("unroll")                                                        \
    for (int m = 0; m < RB; ++m) {                                           \
        const bool rv = !BORDER || (unsigned)(yS + m) < 256u;                \
        _Pragma("unroll")                                                    \
        for (int i = 0; i < 4; ++i) {                                        \
            float tv = tval_s(og[DEPTH + m][i]);                             \
            tin[m][i] = rv ? tv : 0.f;                                       \
        }                                                                    \
    }                                                                        \
    /* scale current rows to Z-domain (loads now have ~stage-0 of cover) */  \
    _Pragma("unroll")                                                        \
    for (int t = 0; t < DEPTH; ++t)                                          \
        { _Pragma("unroll") for (int i = 0; i < 4; ++i) og[t][i] *= AZS; }   \
    _Pragma("unroll")                                                        \
    for (int k = 1; k <= DEPTH; ++k) {                                       \
        float hn[RB][4];                                                     \
        _Pragma("unroll")                                                    \
        for (int m = 0; m < RB; ++m) {                                       \
            float lft = __int_as_float(__builtin_amdgcn_ds_bpermute(a_up, __float_as_int(tin[m][3]))); \
            float rgt = __int_as_float(__builtin_amdgcn_ds_bpermute(a_dn, __float_as_int(tin[m][0]))); \
            hn[m][0] = fmaf(w1s, tin[m][0], fmaf(w0s, tin[m][1], w0L * lft)); \
            hn[m][1] = fmaf(w1s, tin[m][1], w0s * (tin[m][0] + tin[m][2]));  \
            hn[m][2] = fmaf(w1s, tin[m][2], w0s * (tin[m][1] + tin[m][3]));  \
            hn[m][3] = fmaf(w1s, tin[m][3], fmaf(w0s, tin[m][2], w0R * rgt)); \
        }                                                                    \
        _Pragma("unroll")                                                    \
        for (int m = 0; m < RB; ++m) {                                       \
            const bool rv = !BORDER || (unsigned)(yS - k + m) < 256u;        \
            _Pragma("unroll")                                                \
            for (int i = 0; i < 4; ++i) {                                    \
                float h_im1 = (m == 0) ? hA[k - 1][i] : (m == 1) ? hB[k - 1][i] : hn[m - 2][i]; \
                float h_i   = (m == 0) ? hB[k - 1][i] : hn[m - 1][i];        \
                float Z = fmaf(W0Z, h_im1 + hn[m][i],                        \
                          fmaf(W1Z, h_i, og[DEPTH - k + m][i]));             \
                if (k < DEPTH) { float tv = tval_s(Z); tin[m][i] = rv ? tv : 0.f; } \
                else           { tin[m][i] = uval_s(Z); }                    \
            }                                                                \
        }                                                                    \
        _Pragma("unroll")                                                    \
        for (int i = 0; i < 4; ++i) { hA[k - 1][i] = hn[2][i]; hB[k - 1][i] = hn[3][i]; } \
    }                                                                        \
    _Pragma("unroll")                                                        \
    for (int m = 0; m < RB; ++m) {                                           \
        const int r = yS - DEPTH + m;                                        \
        if (r >= y0 && r < y0 + ROWS) {                                      \
            f4 v; v.x = tin[m][0]; v.y = tin[m][1]; v.z = tin[m][2]; v.w = tin[m][3]; \
            *reinterpret_cast<f4*>(up_lane + r * Ww) = v;                    \
        }                                                                    \
    }                                                                        \
} while (0)

// Round-12 occupancy pivot: grid was the 2-waves/SIMD limiter (2048 waves /
// 1024 SIMDs). STRIPS=8 -> 4096 waves = 4/SIMD; waves_per_eu(4,4) caps the
// allocator at 128 VGPRs (current use: 100 -> no spill expected; guard
// signal is WRITE_SIZE == 131072 KB exactly).
__global__ __launch_bounds__(64)
__attribute__((amdgpu_waves_per_eu(4, 4)))
void k_fused(const float* __restrict__ o, const float* __restrict__ sigma,
             const float* __restrict__ lam, float* __restrict__ out) {
    const int lane  = threadIdx.x;
    const int bid   = blockIdx.x;
    const int plane = bid >> 3;               // 512 planes
    const int strip = bid & 7;
    const int y0    = strip * ROWS;
    const int ch    = plane & 63;

    float s   = fmaxf(sigma[ch], 1e-6f);
    float eg  = __expf(-1.0f / (2.0f * s * s));
    float inv = 1.0f / (1.0f + 2.0f * eg);
    const float w0s = eg * inv, w1s = inv, l = lam[0];
    const float W0Z = -l * w0s * AZS;         // vertical taps, -lam and AZS folded
    const float W1Z = -l * w1s * AZS;
    // edge-lane masked taps: kill the per-stage cndmask on lft/rgt
    const float w0L = (lane == 0)  ? 0.f : w0s;
    const float w0R = (lane == 63) ? 0.f : w0s;

    const float* op_lane = o   + plane * HW + lane * 4;
    float*       up_lane = out + plane * HW + lane * 4;
    const int a_up = ((lane + 63) & 63) << 2;
    const int a_dn = ((lane + 1)  & 63) << 2;

    // per-stage h carries: rows (r-1, r) of conv'd t_{k-1}, in registers
    float hA[DEPTH][4], hB[DEPTH][4];
#pragma unroll
    for (int k = 0; k < DEPTH; ++k)
#pragma unroll
        for (int i = 0; i < 4; ++i) { hA[k][i] = 0.f; hB[k][i] = 0.f; }

    // prologue: prefetch first step's stage-0 rows (y0-10..y0-7, clamped;
    // OOB rows are zeroed by the border steps' rv select before use)
    float pnext[RB][4];
#pragma unroll
    for (int m = 0; m < RB; ++m) {
        int r = y0 - DEPTH + m;
        r = r < 0 ? 0 : (r > 255 ? 255 : r);
        f4 v = *reinterpret_cast<const f4*>(op_lane + r * Ww);
        pnext[m][0] = v.x; pnext[m][1] = v.y; pnext[m][2] = v.z; pnext[m][3] = v.w;
    }

    // border-step bounds: steps touching rows <0 (strip 0) or >255 (strip 7)
    int jb0 = (20 - y0 + 3) / 4; if (jb0 < 0) jb0 = 0;            // first interior
    int jb1 = (262 - y0) / 4 + 1; if (jb1 > NSTEP) jb1 = NSTEP;   // first trailing border

    int j = 0;
#pragma unroll 1
    for (; j < jb0; ++j)  { const int yS = y0 - DEPTH + RB * j; STEP_BODY(true);  }
#pragma unroll 1
    for (; j < jb1; ++j)  { const int yS = y0 - DEPTH + RB * j; STEP_BODY(false); }
#pragma unroll 1
    for (; j < NSTEP; ++j){ const int yS = y0 - DEPTH + RB * j; STEP_BODY(true);  }
}

extern "C" void kernel_launch(void* const* d_in, const int* in_sizes, int n_in,
                              void* d_out, int out_size, void* d_ws, size_t ws_size,
                              hipStream_t stream) {
    (void)in_sizes; (void)n_in; (void)out_size; (void)d_ws; (void)ws_size;
    const float* o     = (const float*)d_in[0];
    const float* sigma = (const float*)d_in[1];
    const float* lam   = (const float*)d_in[2];
    float* out = (float*)d_out;

    k_fused<<<PLANES * STRIPS, 64, 0, stream>>>(o, sigma, lam, out);
}

// Round 13
// 170.514 us; speedup vs baseline: 1.8537x; 1.8537x over previous
//
#include <hip/hip_runtime.h>

typedef float f4 __attribute__((ext_vector_type(4)));

static constexpr int Hh = 256, Ww = 256, HW = Hh * Ww;
static constexpr int PLANES = 512;            // N*C
static constexpr int STRIPS = 6;              // 3072 waves = 3 waves/SIMD
static constexpr int DEPTH  = 10;
static constexpr int RB     = 4;              // rows advanced per sweep step

#if __has_builtin(__builtin_amdgcn_exp2f)
#define EXP2F(x) __builtin_amdgcn_exp2f(x)
#else
#define EXP2F(x) __expf((x) * 0.6931471805599453f)
#endif

static constexpr float LN2 = 0.6931471805599453f;
static constexpr float L2E = 1.4426950408889634f;
static constexpr float AZS = 10.0f * L2E;     // Z = AZS * z  (BETA+log2e folded)

// slrelu pieces in Z-domain (Z = 10*log2e*z):
//   ln(1+p), p = 2^(-|Z|), deg-2 minimax  p*(A1 + A2*p), |err| <= 1.4e-2
//   (error budget OK: absmax saturated at 2.0 across rounds; threshold 10.04)
//   max(Z,0) = (Z + |Z|)/2 folded into linear coefficients.
static constexpr float A1 = 0.9897f;
static constexpr float A2 = -0.3059f;
// t = 1 - 2*slrelu(z) = 1 + TA*Z + TB*az + TC*ln(1+p),  TC = -0.16 exactly
static constexpr float TA = -0.12f * LN2;
static constexpr float TB = -0.08f * LN2;
static constexpr float TCA1 = -0.16f * A1;
static constexpr float TCA2 = -0.16f * A2;
// u = slrelu(z) = UA*Z + UB*az + UC*ln(1+p),  UC = 0.08 exactly
static constexpr float UA = 0.06f * LN2;
static constexpr float UB = 0.04f * LN2;
static constexpr float UCA1 = 0.08f * A1;
static constexpr float UCA2 = 0.08f * A2;

// 6 ops: az, exp2, 4 fma
__device__ __forceinline__ float tval_s(float Z) {
    float az = fabsf(Z);
    float p  = EXP2F(-az);                    // neg folds into src modifier
    float r  = fmaf(TCA2, p, TCA1);
    float s  = fmaf(r, p, 1.0f);              // 1 + TC*ln(1+p)
    return fmaf(TA, Z, fmaf(TB, az, s));
}
// 6 ops
__device__ __forceinline__ float uval_s(float Z) {
    float az = fabsf(Z);
    float p  = EXP2F(-az);
    float r  = fmaf(UCA2, p, UCA1);
    float su = r * p;                         // UC*ln(1+p)
    return fmaf(UA, Z, fmaf(UB, az, su));
}

// One sweep step. BORDER is a literal; pnext[4][4] carries the next step's
// stage-0 rows (prefetched one full step ahead -> no vmcnt stall at stage 0).
#define STEP_BODY(BORDER) do {                                               \
    float og[DEPTH + RB][4];                                                 \
    /* stage-0 rows: consume prefetch (long since returned), scale to Z */   \
    _Pragma("unroll")                                                        \
    for (int m = 0; m < RB; ++m)                                             \
        { _Pragma("unroll") for (int i = 0; i < 4; ++i) og[DEPTH + m][i] = AZS * pnext[m][i]; } \
    /* issue current-step rows og[9]..og[0] in consumption order (raw) */    \
    _Pragma("unroll")                                                        \
    for (int t = DEPTH - 1; t >= 0; --t) {                                   \
        int r = yS - DEPTH + t;                                              \
        if (BORDER) r = r < 0 ? 0 : (r > 255 ? 255 : r);                     \
        f4 v = *reinterpret_cast<const f4*>(op_lane + r * Ww);               \
        og[t][0] = v.x; og[t][1] = v.y; og[t][2] = v.z; og[t][3] = v.w;      \
    }                                                                        \
    /* issue NEXT step's stage-0 prefetch (rows yS+4..yS+7, always clamped) */\
    _Pragma("unroll")                                                        \
    for (int m = 0; m < RB; ++m) {                                           \
        int r = yS + RB + m;                                                 \
        r = r < 0 ? 0 : (r > 255 ? 255 : r);                                 \
        f4 v = *reinterpret_cast<const f4*>(op_lane + r * Ww);               \
        pnext[m][0] = v.x; pnext[m][1] = v.y; pnext[m][2] = v.z; pnext[m][3] = v.w; \
    }                                                                        \
    asm volatile("" ::: "memory");               /* pin loads above compute */\
    float tin[RB][4];                                                        \
    _Pragma("unroll")                                                        \
    for (int m = 0; m < RB; ++m) {                                           \
        const bool rv = !BORDER || (unsigned)(yS + m) < 256u;                \
        _Pragma("unroll")                                                    \
        for (int i = 0; i < 4; ++i) {                                        \
            float tv = tval_s(og[DEPTH + m][i]);                             \
            tin[m][i] = rv ? tv : 0.f;                                       \
        }                                                                    \
    }                                                                        \
    /* scale current rows to Z-domain (loads now have ~stage-0 of cover) */  \
    _Pragma("unroll")                                                        \
    for (int t = 0; t < DEPTH; ++t)                                          \
        { _Pragma("unroll") for (int i = 0; i < 4; ++i) og[t][i] *= AZS; }   \
    _Pragma("unroll")                                                        \
    for (int k = 1; k <= DEPTH; ++k) {                                       \
        float hn[RB][4];                                                     \
        _Pragma("unroll")                                                    \
        for (int m = 0; m < RB; ++m) {                                       \
            float lft = __int_as_float(__builtin_amdgcn_ds_bpermute(a_up, __float_as_int(tin[m][3]))); \
            float rgt = __int_as_float(__builtin_amdgcn_ds_bpermute(a_dn, __float_as_int(tin[m][0]))); \
            hn[m][0] = fmaf(w1s, tin[m][0], fmaf(w0s, tin[m][1], w0L * lft)); \
            hn[m][1] = fmaf(w1s, tin[m][1], w0s * (tin[m][0] + tin[m][2]));  \
            hn[m][2] = fmaf(w1s, tin[m][2], w0s * (tin[m][1] + tin[m][3]));  \
            hn[m][3] = fmaf(w1s, tin[m][3], fmaf(w0s, tin[m][2], w0R * rgt)); \
        }                                                                    \
        _Pragma("unroll")                                                    \
        for (int m = 0; m < RB; ++m) {                                       \
            const bool rv = !BORDER || (unsigned)(yS - k + m) < 256u;        \
            _Pragma("unroll")                                                \
            for (int i = 0; i < 4; ++i) {                                    \
                float h_im1 = (m == 0) ? hA[k - 1][i] : (m == 1) ? hB[k - 1][i] : hn[m - 2][i]; \
                float h_i   = (m == 0) ? hB[k - 1][i] : hn[m - 1][i];        \
                float Z = fmaf(W0Z, h_im1 + hn[m][i],                        \
                          fmaf(W1Z, h_i, og[DEPTH - k + m][i]));             \
                if (k < DEPTH) { float tv = tval_s(Z); tin[m][i] = rv ? tv : 0.f; } \
                else           { tin[m][i] = uval_s(Z); }                    \
            }                                                                \
        }                                                                    \
        _Pragma("unroll")                                                    \
        for (int i = 0; i < 4; ++i) { hA[k - 1][i] = hn[2][i]; hB[k - 1][i] = hn[3][i]; } \
    }                                                                        \
    _Pragma("unroll")                                                        \
    for (int m = 0; m < RB; ++m) {                                           \
        const int r = yS - DEPTH + m;                                        \
        if (r >= y0 && r < y1) {                                             \
            f4 v; v.x = tin[m][0]; v.y = tin[m][1]; v.z = tin[m][2]; v.w = tin[m][3]; \
            *reinterpret_cast<f4*>(up_lane + r * Ww) = v;                    \
        }                                                                    \
    }                                                                        \
} while (0)

// waves_per_eu(2,2): the PROVEN non-spilling allocator target (VGPR=100,
// WRITE_SIZE exactly = output). Round-12 showed (4,4) collapses the
// allocator to 64 VGPRs and spills ~550 MB to HBM — occupancy is raised
// via the GRID instead: VGPR=100 <= 128 so hardware residency allows
// 4 waves/SIMD; 3072 waves give exactly 3/SIMD with unchanged codegen.
__global__ __launch_bounds__(64)
__attribute__((amdgpu_waves_per_eu(2, 2)))
void k_fused(const float* __restrict__ o, const float* __restrict__ sigma,
             const float* __restrict__ lam, float* __restrict__ out) {
    const int lane  = threadIdx.x;
    const int bid   = blockIdx.x;
    const int plane = bid / STRIPS;           // 512 planes
    const int strip = bid % STRIPS;
    const int y0    = (strip * 256) / STRIPS;       // 0,42,85,128,170,213
    const int y1    = ((strip + 1) * 256) / STRIPS; // 42,85,128,170,213,256
    const int ch    = plane & 63;

    float s   = fmaxf(sigma[ch], 1e-6f);
    float eg  = __expf(-1.0f / (2.0f * s * s));
    float inv = 1.0f / (1.0f + 2.0f * eg);
    const float w0s = eg * inv, w1s = inv, l = lam[0];
    const float W0Z = -l * w0s * AZS;         // vertical taps, -lam and AZS folded
    const float W1Z = -l * w1s * AZS;
    // edge-lane masked taps: kill the per-stage cndmask on lft/rgt
    const float w0L = (lane == 0)  ? 0.f : w0s;
    const float w0R = (lane == 63) ? 0.f : w0s;

    const float* op_lane = o   + plane * HW + lane * 4;
    float*       up_lane = out + plane * HW + lane * 4;
    const int a_up = ((lane + 63) & 63) << 2;
    const int a_dn = ((lane + 1)  & 63) << 2;

    // per-stage h carries: rows (r-1, r) of conv'd t_{k-1}, in registers
    float hA[DEPTH][4], hB[DEPTH][4];
#pragma unroll
    for (int k = 0; k < DEPTH; ++k)
#pragma unroll
        for (int i = 0; i < 4; ++i) { hA[k][i] = 0.f; hB[k][i] = 0.f; }

    // prologue: prefetch first step's stage-0 rows (y0-10..y0-7, clamped;
    // OOB rows are zeroed by the border steps' rv select before use)
    float pnext[RB][4];
#pragma unroll
    for (int m = 0; m < RB; ++m) {
        int r = y0 - DEPTH + m;
        r = r < 0 ? 0 : (r > 255 ? 255 : r);
        f4 v = *reinterpret_cast<const f4*>(op_lane + r * Ww);
        pnext[m][0] = v.x; pnext[m][1] = v.y; pnext[m][2] = v.z; pnext[m][3] = v.w;
    }

    // sweep-step count for this strip (rows + 2*DEPTH overhead, /RB rounded up)
    const int nstep = (y1 - y0 + 2 * DEPTH + RB - 1) / RB;   // 16 for all strips
    // border-step bounds: steps touching rows <0 (strip 0) or >255 (last strip)
    int jb0 = (20 - y0 + 3) / 4; if (jb0 < 0) jb0 = 0;           // first interior
    int jb1 = (262 - y0) / 4 + 1; if (jb1 > nstep) jb1 = nstep;  // first trailing border

    int j = 0;
#pragma unroll 1
    for (; j < jb0; ++j)  { const int yS = y0 - DEPTH + RB * j; STEP_BODY(true);  }
#pragma unroll 1
    for (; j < jb1; ++j)  { const int yS = y0 - DEPTH + RB * j; STEP_BODY(false); }
#pragma unroll 1
    for (; j < nstep; ++j){ const int yS = y0 - DEPTH + RB * j; STEP_BODY(true);  }
}

extern "C" void kernel_launch(void* const* d_in, const int* in_sizes, int n_in,
                              void* d_out, int out_size, void* d_ws, size_t ws_size,
                              hipStream_t stream) {
    (void)in_sizes; (void)n_in; (void)out_size; (void)d_ws; (void)ws_size;
    const float* o     = (const float*)d_in[0];
    const float* sigma = (const float*)d_in[1];
    const float* lam   = (const float*)d_in[2];
    float* out = (float*)d_out;

    k_fused<<<PLANES * STRIPS, 64, 0, stream>>>(o, sigma, lam, out);
}